// Round 3
// baseline (276.746 us; speedup 1.0000x reference)
//
#include <hip/hip_runtime.h>
#include <math.h>

#define LBL 26
#define MM  14
#define FF  128
#define HH  16
#define WW  8
#define KSZ 5
#define WPB 16              // words per block (fused fallback)
#define LPB (WPB * MM)      // 224
#define NITER 8

// ---------------- kernel 1: fold conv into emission weights ----------------
__global__ void prep_kernel(const float* __restrict__ K,
                            const float* __restrict__ b,
                            const float* __restrict__ W,
                            float* __restrict__ w2,
                            float* __restrict__ cvec) {
    int idx = blockIdx.x * blockDim.x + threadIdx.x;
    int stride = gridDim.x * blockDim.x;
    for (int o = idx; o < LBL * FF; o += stride) {
        int l = o / FF, f = o % FF;
        int qy = f / WW, qx = f % WW;
        double acc = 0.0;
        for (int ky = 0; ky < KSZ; ++ky) {
            int y = qy - ky + 2;
            if (y < 0 || y >= HH) continue;
            for (int kx = 0; kx < KSZ; ++kx) {
                int x = qx - kx + 2;
                if (x < 0 || x >= WW) continue;
                acc += (double)K[ky * KSZ + kx] * (double)W[l * FF + y * WW + x];
            }
        }
        w2[o] = (float)acc;
    }
    for (int l = idx; l < LBL; l += stride) {
        double s = 0.0;
        for (int f = 0; f < FF; ++f) s += (double)W[l * FF + f];
        cvec[l] = (float)(s * (double)b[0]);
    }
}

__device__ __forceinline__ void gload_lds16(const void* g, void* l) {
    __builtin_amdgcn_global_load_lds(
        (const __attribute__((address_space(1))) void*)g,
        (__attribute__((address_space(3))) void*)l, 16, 0, 0);
}

// ---------------- kernel A: emission scores (barrier-free, per-wave pipeline) ----------------
// thread = one letter; wave-private dbuf LDS tile; gll-staged; sT[l][letter] coalesced out.
__global__ __launch_bounds__(256) void scores_kernel(const float* __restrict__ X,
                                                     const float* __restrict__ w2,
                                                     const float* __restrict__ cvec,
                                                     float* __restrict__ sT,
                                                     int NLET) {
    __shared__ float4 tile[4 * 2 * 64 * 4];  // [wave][buf][letter][sub] = 32 KiB

    const int tid  = threadIdx.x;
    const int wv   = tid >> 6;
    const int lane = tid & 63;
    const int lbase = blockIdx.x * 256 + wv * 64;   // wave's first letter

    const float4* X4 = (const float4*)X;
    // source pre-swizzle (rule #21: swizzle source + read, LDS dest stays linear)
    const int srcsub = (lane & 3) ^ ((lane >> 3) & 3);
    const size_t src_base = (size_t)(lbase + (lane >> 2)) * 32 + (size_t)srcsub;  // float4 units
    float4* twave = tile + wv * 512;

    float acc[LBL];
#pragma unroll
    for (int l = 0; l < LBL; ++l) acc[l] = cvec[l];   // uniform -> s_load

    const float4* W4 = (const float4*)w2;
    const int swp = (lane >> 1) & 3;

#define ISSUE(c, buf)                                                              \
    {                                                                              \
        float4* dstb = twave + (buf) * 256;                                        \
        _Pragma("unroll")                                                          \
        for (int k = 0; k < 4; ++k) {                                              \
            gload_lds16((const void*)(X4 + src_base + (size_t)k * 512 + (c) * 4),  \
                        (void*)(dstb + k * 64));                                   \
        }                                                                          \
    }

    ISSUE(0, 0)
#pragma unroll
    for (int c = 0; c < 8; ++c) {
        if (c < 7) {
            ISSUE(c + 1, (c + 1) & 1)
            asm volatile("s_waitcnt vmcnt(4)" ::: "memory");  // current chunk landed, next in flight
        } else {
            asm volatile("s_waitcnt vmcnt(0)" ::: "memory");
        }
        const float4* tb = twave + (c & 1) * 256 + lane * 4;
        const float4 xv0 = tb[swp];          // logical sub 0
        const float4 xv1 = tb[1 ^ swp];
        const float4 xv2 = tb[2 ^ swp];
        const float4 xv3 = tb[3 ^ swp];
#pragma unroll
        for (int l = 0; l < LBL; ++l) {
            const float4 w0 = W4[l * 32 + c * 4 + 0];   // uniform -> s_load
            const float4 w1 = W4[l * 32 + c * 4 + 1];
            const float4 w2v = W4[l * 32 + c * 4 + 2];
            const float4 w3 = W4[l * 32 + c * 4 + 3];
            float a = acc[l];
            a = fmaf(xv0.x, w0.x, a); a = fmaf(xv0.y, w0.y, a);
            a = fmaf(xv0.z, w0.z, a); a = fmaf(xv0.w, w0.w, a);
            a = fmaf(xv1.x, w1.x, a); a = fmaf(xv1.y, w1.y, a);
            a = fmaf(xv1.z, w1.z, a); a = fmaf(xv1.w, w1.w, a);
            a = fmaf(xv2.x, w2v.x, a); a = fmaf(xv2.y, w2v.y, a);
            a = fmaf(xv2.z, w2v.z, a); a = fmaf(xv2.w, w2v.w, a);
            a = fmaf(xv3.x, w3.x, a); a = fmaf(xv3.y, w3.y, a);
            a = fmaf(xv3.z, w3.z, a); a = fmaf(xv3.w, w3.w, a);
            acc[l] = a;
        }
    }
#undef ISSUE

    const int letter = lbase + lane;
#pragma unroll
    for (int l = 0; l < LBL; ++l)
        sT[(size_t)l * NLET + letter] = acc[l];   // coalesced per instr
}

// ---------------- kernel B: Viterbi decode (barrier-free, 2 words per wave) ----------------
__global__ __launch_bounds__(256) void viterbi_kernel(const float* __restrict__ sT,
                                                      const float* __restrict__ Tm,
                                                      int* __restrict__ out,
                                                      int NLET) {
    __shared__ float vb[8 * 32];   // per-word v-vectors (wave-private pairs)

    const int tid  = threadIdx.x;
    const int wv   = tid >> 6;
    const int lane = tid & 63;
    const int half = lane >> 5;
    const int j    = lane & 31;
    const int jc   = (j < LBL) ? j : 0;

    const int wl   = wv * 2 + half;             // word slot in block
    const int word = blockIdx.x * 8 + wl;

    // prefetch this lane's emission scores (row jc, 14 consecutive) and T column
    float s[MM];
#pragma unroll
    for (int t = 0; t < MM; ++t) s[t] = sT[(size_t)jc * NLET + word * MM + t];
    float tcol[LBL];
#pragma unroll
    for (int i = 0; i < LBL; ++i) tcol[i] = Tm[i * LBL + jc];

    float* vbw = vb + wl * 32;
    float v = (j < LBL) ? s[0] : -INFINITY;
    if (j < LBL) vbw[j] = v;
    unsigned bp_pack[4] = {0u, 0u, 0u, 0u};

#pragma unroll
    for (int t = 1; t < MM; ++t) {
        const float4* q = (const float4*)vbw;
        const float4 q0 = q[0], q1 = q[1], q2 = q[2], q3 = q[3], q4 = q[4], q5 = q[5], q6 = q[6];
        float vals[LBL];
#define VSET(i, Q, C) vals[i] = Q.C + tcol[i];
        VSET(0, q0, x) VSET(1, q0, y) VSET(2, q0, z) VSET(3, q0, w)
        VSET(4, q1, x) VSET(5, q1, y) VSET(6, q1, z) VSET(7, q1, w)
        VSET(8, q2, x) VSET(9, q2, y) VSET(10, q2, z) VSET(11, q2, w)
        VSET(12, q3, x) VSET(13, q3, y) VSET(14, q3, z) VSET(15, q3, w)
        VSET(16, q4, x) VSET(17, q4, y) VSET(18, q4, z) VSET(19, q4, w)
        VSET(20, q5, x) VSET(21, q5, y) VSET(22, q5, z) VSET(23, q5, w)
        VSET(24, q6, x) VSET(25, q6, y)
#undef VSET
        // max tree (depth 5; value identical to sequential max)
        float u0 = fmaxf(vals[0], vals[13]), u1 = fmaxf(vals[1], vals[14]);
        float u2 = fmaxf(vals[2], vals[15]), u3 = fmaxf(vals[3], vals[16]);
        float u4 = fmaxf(vals[4], vals[17]), u5 = fmaxf(vals[5], vals[18]);
        float u6 = fmaxf(vals[6], vals[19]), u7 = fmaxf(vals[7], vals[20]);
        float u8 = fmaxf(vals[8], vals[21]), u9 = fmaxf(vals[9], vals[22]);
        float u10 = fmaxf(vals[10], vals[23]), u11 = fmaxf(vals[11], vals[24]);
        float u12 = fmaxf(vals[12], vals[25]);
        float w0 = fmaxf(u0, u7), w1 = fmaxf(u1, u8), w2_ = fmaxf(u2, u9);
        float w3 = fmaxf(u3, u10), w4 = fmaxf(u4, u11), w5 = fmaxf(u5, u12);
        float x0 = fmaxf(w0, w3), x1 = fmaxf(w1, w4), x2 = fmaxf(w2_, w5);
        float y0 = fmaxf(x0, x1), y1 = fmaxf(x2, u6);
        const float best = fmaxf(y0, y1);
        // first-occurrence argmax: bit i set iff vals[i]==best; take lowest set bit
        unsigned m = 0u;
#pragma unroll
        for (int i = LBL - 1; i >= 0; --i) m = m + m + (vals[i] == best ? 1u : 0u);
        const int bi = __builtin_ctz(m);

        v = (j < LBL) ? (best + s[t]) : -INFINITY;
        if (j < LBL) vbw[j] = v;
        const int k = t - 1;
        bp_pack[k >> 2] |= (unsigned)bi << ((k & 3) * 8);
    }

    // argmax over j of final v (within 32-lane half), first occurrence
    float best = v;
    int bidx = (j < LBL) ? j : 999;
#pragma unroll
    for (int d = 1; d < 32; d <<= 1) {
        const float ov = __shfl_xor(best, d, 64);
        const int oi = __shfl_xor(bidx, d, 64);
        if (ov > best || (ov == best && oi < bidx)) { best = ov; bidx = oi; }
    }

    int cur = bidx;
    if (j == 0) out[word * MM + (MM - 1)] = cur;
#pragma unroll
    for (int k = MM - 2; k >= 0; --k) {
        const unsigned packed = __shfl(bp_pack[k >> 2], (lane & 32) | cur, 64);
        cur = (int)((packed >> ((k & 3) * 8)) & 0xffu);
        if (j == 0) out[word * MM + k] = cur;
    }
}

// ---------------- fallback: round-2 fused kernel (used if d_ws too small) ----------------
__global__ __launch_bounds__(256) void crf_kernel(const float* __restrict__ X,
                                                  const float* __restrict__ T,
                                                  const float* __restrict__ w2,
                                                  const float* __restrict__ cvec,
                                                  int* __restrict__ out) {
    __shared__ float4 tile[LPB * 4];
    __shared__ float  s_lds[WPB * MM * LBL];
    __shared__ float  v_lds[WPB * 32];

    const int tid = threadIdx.x;
    const int blk = blockIdx.x;
    const float4* X4 = (const float4*)X + (size_t)blk * LPB * (FF / 4);
    const float4* W4 = (const float4*)w2;

    float acc[LBL];
    if (tid < LPB) {
#pragma unroll
        for (int l = 0; l < LBL; ++l) acc[l] = cvec[l];
    }
    const int c0 = tid, c1 = tid + 256, c2 = tid + 512, c3 = tid + 768;
    float4 st0, st1, st2, st3;
    st0 = X4[(c0 >> 2) * 32 + (c0 & 3)];
    st1 = X4[(c1 >> 2) * 32 + (c1 & 3)];
    st2 = X4[(c2 >> 2) * 32 + (c2 & 3)];
    if (tid < 128) st3 = X4[(c3 >> 2) * 32 + (c3 & 3)];

    for (int iter = 0; iter < NITER; ++iter) {
        tile[(c0 >> 2) * 4 + ((c0 & 3) ^ ((c0 >> 2) & 3))] = st0;
        tile[(c1 >> 2) * 4 + ((c1 & 3) ^ ((c1 >> 2) & 3))] = st1;
        tile[(c2 >> 2) * 4 + ((c2 & 3) ^ ((c2 >> 2) & 3))] = st2;
        if (tid < 128) tile[(c3 >> 2) * 4 + ((c3 & 3) ^ ((c3 >> 2) & 3))] = st3;
        __syncthreads();
        if (iter + 1 < NITER) {
            const int ofs = (iter + 1) * 4;
            st0 = X4[(c0 >> 2) * 32 + ofs + (c0 & 3)];
            st1 = X4[(c1 >> 2) * 32 + ofs + (c1 & 3)];
            st2 = X4[(c2 >> 2) * 32 + ofs + (c2 & 3)];
            if (tid < 128) st3 = X4[(c3 >> 2) * 32 + ofs + (c3 & 3)];
        }
        if (tid < LPB) {
            const float4 xv0 = tile[tid * 4 + (0 ^ (tid & 3))];
            const float4 xv1 = tile[tid * 4 + (1 ^ (tid & 3))];
            const float4 xv2 = tile[tid * 4 + (2 ^ (tid & 3))];
            const float4 xv3 = tile[tid * 4 + (3 ^ (tid & 3))];
#pragma unroll
            for (int l = 0; l < LBL; ++l) {
                const float4 w0 = W4[l * 32 + iter * 4 + 0];
                const float4 w1 = W4[l * 32 + iter * 4 + 1];
                const float4 w2v = W4[l * 32 + iter * 4 + 2];
                const float4 w3 = W4[l * 32 + iter * 4 + 3];
                float a = acc[l];
                a = fmaf(xv0.x, w0.x, a); a = fmaf(xv0.y, w0.y, a);
                a = fmaf(xv0.z, w0.z, a); a = fmaf(xv0.w, w0.w, a);
                a = fmaf(xv1.x, w1.x, a); a = fmaf(xv1.y, w1.y, a);
                a = fmaf(xv1.z, w1.z, a); a = fmaf(xv1.w, w1.w, a);
                a = fmaf(xv2.x, w2v.x, a); a = fmaf(xv2.y, w2v.y, a);
                a = fmaf(xv2.z, w2v.z, a); a = fmaf(xv2.w, w2v.w, a);
                a = fmaf(xv3.x, w3.x, a); a = fmaf(xv3.y, w3.y, a);
                a = fmaf(xv3.z, w3.z, a); a = fmaf(xv3.w, w3.w, a);
                acc[l] = a;
            }
        }
        __syncthreads();
    }
    if (tid < LPB) {
#pragma unroll
        for (int l = 0; l < LBL; ++l) s_lds[tid * LBL + l] = acc[l];
    }
    __syncthreads();

    const int lane = tid & 63;
    const int wvid = tid >> 6;
    const int half = lane >> 5;
    const int j = lane & 31;
    const int jc = (j < LBL) ? j : 0;

    float tcol[LBL];
#pragma unroll
    for (int i = 0; i < LBL; ++i) tcol[i] = T[i * LBL + jc];

    for (int pass = 0; pass < 2; ++pass) {
        const int wi = pass * 8 + wvid * 2 + half;
        const int word = blk * WPB + wi;
        const float* sw = s_lds + wi * MM * LBL;
        float* vbp = v_lds + wi * 32;

        float v = (j < LBL) ? sw[j] : -INFINITY;
        if (j < LBL) vbp[j] = v;
        unsigned bp_pack[4] = {0u, 0u, 0u, 0u};

#pragma unroll
        for (int t = 1; t < MM; ++t) {
            float best = -INFINITY;
            int bi = 0;
#define VCHK(vexpr, idx) { const float val = (vexpr) + tcol[idx]; \
                           if (val > best) { best = val; bi = idx; } }
            {
                float4 vv;
                vv = *(const float4*)(vbp + 0);
                VCHK(vv.x, 0) VCHK(vv.y, 1) VCHK(vv.z, 2) VCHK(vv.w, 3)
                vv = *(const float4*)(vbp + 4);
                VCHK(vv.x, 4) VCHK(vv.y, 5) VCHK(vv.z, 6) VCHK(vv.w, 7)
                vv = *(const float4*)(vbp + 8);
                VCHK(vv.x, 8) VCHK(vv.y, 9) VCHK(vv.z, 10) VCHK(vv.w, 11)
                vv = *(const float4*)(vbp + 12);
                VCHK(vv.x, 12) VCHK(vv.y, 13) VCHK(vv.z, 14) VCHK(vv.w, 15)
                vv = *(const float4*)(vbp + 16);
                VCHK(vv.x, 16) VCHK(vv.y, 17) VCHK(vv.z, 18) VCHK(vv.w, 19)
                vv = *(const float4*)(vbp + 20);
                VCHK(vv.x, 20) VCHK(vv.y, 21) VCHK(vv.z, 22) VCHK(vv.w, 23)
                vv = *(const float4*)(vbp + 24);
                VCHK(vv.x, 24) VCHK(vv.y, 25)
            }
#undef VCHK
            v = (j < LBL) ? (best + sw[t * LBL + j]) : -INFINITY;
            if (j < LBL) vbp[j] = v;
            const int k = t - 1;
            bp_pack[k >> 2] |= (unsigned)bi << ((k & 3) * 8);
        }

        float best = v;
        int bidx = (j < LBL) ? j : 999;
#pragma unroll
        for (int d = 1; d < 32; d <<= 1) {
            const float ov = __shfl_xor(best, d, 64);
            const int oi = __shfl_xor(bidx, d, 64);
            if (ov > best || (ov == best && oi < bidx)) { best = ov; bidx = oi; }
        }
        int cur = bidx;
        if (j == 0) out[word * MM + (MM - 1)] = cur;
#pragma unroll
        for (int k = MM - 2; k >= 0; --k) {
            const unsigned packed = __shfl(bp_pack[k >> 2], (lane & 32) | cur, 64);
            cur = (int)((packed >> ((k & 3) * 8)) & 0xffu);
            if (j == 0) out[word * MM + k] = cur;
        }
        __syncthreads();
    }
}

extern "C" void kernel_launch(void* const* d_in, const int* in_sizes, int n_in,
                              void* d_out, int out_size, void* d_ws, size_t ws_size,
                              hipStream_t stream) {
    const float* X = (const float*)d_in[0];
    const float* K = (const float*)d_in[1];
    const float* b = (const float*)d_in[2];
    const float* W = (const float*)d_in[3];
    const float* T = (const float*)d_in[4];
    int* out = (int*)d_out;

    const int nw = in_sizes[0] / (MM * FF);     // 32768 words
    const int NLET = nw * MM;                   // 458752 letters

    const size_t sT_bytes = (size_t)LBL * NLET * sizeof(float);   // ~47.7 MB
    const size_t w_bytes  = (size_t)(LBL * FF + LBL) * sizeof(float);

    if (ws_size >= sT_bytes + w_bytes && (NLET % 256) == 0 && (nw % 8) == 0) {
        float* sT   = (float*)d_ws;
        float* w2   = (float*)((char*)d_ws + sT_bytes);
        float* cvec = w2 + LBL * FF;
        prep_kernel<<<(LBL * FF + 255) / 256, 256, 0, stream>>>(K, b, W, w2, cvec);
        scores_kernel<<<NLET / 256, 256, 0, stream>>>(X, w2, cvec, sT, NLET);
        viterbi_kernel<<<nw / 8, 256, 0, stream>>>(sT, T, out, NLET);
    } else {
        float* w2   = (float*)d_ws;
        float* cvec = w2 + LBL * FF;
        prep_kernel<<<(LBL * FF + 255) / 256, 256, 0, stream>>>(K, b, W, w2, cvec);
        crf_kernel<<<nw / WPB, 256, 0, stream>>>(X, T, w2, cvec, out);
    }
}